// Round 1
// baseline (747.032 us; speedup 1.0000x reference)
//
#include <hip/hip_runtime.h>
#include <math.h>

#define F_IN 128
#define H 16
#define C 40
#define K_HOPS 10
#define ALPHA 0.1f
#define BN_EPS 1e-5f

// ---------------- init: deg=1 (self loop), zero agg buffer, zero stats ----------------
__global__ void k_init(float* __restrict__ deg, float* __restrict__ agg,
                       float* __restrict__ stats, int n) {
    int stride = gridDim.x * blockDim.x;
    int total = n * H;
    for (int i = blockIdx.x * blockDim.x + threadIdx.x; i < total; i += stride) {
        agg[i] = 0.0f;
        if (i < n) deg[i] = 1.0f;
        if (i < 2 * H) stats[i] = 0.0f;
    }
}

// ---------------- degree histogram ----------------
__global__ void k_deg(const int* __restrict__ dst, float* __restrict__ deg, int e) {
    int i = blockIdx.x * blockDim.x + threadIdx.x;
    if (i < e) atomicAdd(&deg[dst[i]], 1.0f);
}

// ---------------- dinv = rsqrt(deg), in place ----------------
__global__ void k_dinv(float* __restrict__ deg, int n) {
    int i = blockIdx.x * blockDim.x + threadIdx.x;
    if (i < n) deg[i] = rsqrtf(deg[i]);
}

// ---------------- h1 = x @ W1   [N,128] x [128,16] ----------------
__global__ __launch_bounds__(256) void k_mm1(const float* __restrict__ x,
                                             const float* __restrict__ W1,
                                             float* __restrict__ h1, int n) {
    __shared__ float xs[16 * 132];   // 16 nodes x 128, padded stride 132
    __shared__ float ws[128 * 16];
    int t = threadIdx.x;
    int node0 = blockIdx.x * 16;
#pragma unroll
    for (int r = 0; r < 8; ++r) {
        int idx = t + r * 256;
        int nl = idx >> 7, k = idx & 127;
        int nn = node0 + nl; if (nn >= n) nn = n - 1;
        xs[nl * 132 + k] = x[(size_t)nn * F_IN + k];
        ws[idx] = W1[idx];
    }
    __syncthreads();
    int nl = t >> 4, j = t & 15;
    float acc = 0.0f;
#pragma unroll 8
    for (int k = 0; k < 128; ++k)
        acc = fmaf(xs[nl * 132 + k], ws[k * 16 + j], acc);
    int node = node0 + nl;
    if (node < n) h1[(size_t)node * H + j] = acc;
}

// ---------------- edge aggregation: 16 lanes per edge ----------------
__global__ void k_agg(const int* __restrict__ src, const int* __restrict__ dst,
                      const float* __restrict__ dinv, const float* __restrict__ h,
                      float* __restrict__ agg, int e) {
    int tid = blockIdx.x * blockDim.x + threadIdx.x;
    int edge = tid >> 4;
    if (edge >= e) return;
    int j = tid & 15;
    int s = src[edge], d = dst[edge];
    float nrm = dinv[s] * dinv[d];
    atomicAdd(&agg[(size_t)d * H + j], h[(size_t)s * H + j] * nrm);
}

// ---------------- self-loop + bias + ReLU + BN partial stats ----------------
__global__ __launch_bounds__(256) void k_post1(const float* __restrict__ agg,
                                               const float* __restrict__ h1,
                                               const float* __restrict__ dinv,
                                               const float* __restrict__ b1,
                                               float* __restrict__ hout,
                                               float* __restrict__ stats, int n) {
    __shared__ float sv[256], sq[256];
    int t = threadIdx.x;
    int idx = blockIdx.x * 256 + t;
    int node = idx >> 4, j = idx & 15;
    float v = 0.0f;
    if (node < n) {
        float di = dinv[node];
        v = agg[idx] + di * di * h1[idx] + b1[j];
        v = fmaxf(v, 0.0f);
        hout[idx] = v;
    }
    sv[t] = v; sq[t] = v * v;
    __syncthreads();
    if (t < 16) {
        float s0 = 0.0f, s1 = 0.0f;
#pragma unroll
        for (int r = 0; r < 16; ++r) { s0 += sv[r * 16 + t]; s1 += sq[r * 16 + t]; }
        atomicAdd(&stats[t], s0);
        atomicAdd(&stats[16 + t], s1);
    }
}

// ---------------- BN coefficients: a = gamma*rsqrt(var+eps), c = beta - mean*a ----------------
__global__ void k_bncoef(float* __restrict__ stats, const float* __restrict__ gamma,
                         const float* __restrict__ beta, float nf) {
    int j = threadIdx.x;
    if (j < 16) {
        float mean = stats[j] / nf;
        float var = stats[16 + j] / nf - mean * mean;
        float a = gamma[j] * rsqrtf(var + BN_EPS);
        float c = beta[j] - mean * a;
        stats[j] = a;
        stats[16 + j] = c;
    }
}

// ---------------- BN apply + K_HOPS residual blocks + zero agg2 ----------------
__global__ __launch_bounds__(256) void k_hops(float* __restrict__ h,
                                              float* __restrict__ agg2,
                                              const float* __restrict__ stats,
                                              const float* __restrict__ Wl,
                                              const float* __restrict__ bl, int n) {
    __shared__ float wl[256], bls[16], av[16], cv[16];
    int t = threadIdx.x;
    wl[t] = Wl[t];
    if (t < 16) { bls[t] = bl[t]; av[t] = stats[t]; cv[t] = stats[16 + t]; }
    __syncthreads();
    int node = blockIdx.x * 256 + t;
    if (node >= n) return;
    float hr[16];
    {
        const float4* hp = reinterpret_cast<const float4*>(h + (size_t)node * H);
        float4 v0 = hp[0], v1 = hp[1], v2 = hp[2], v3 = hp[3];
        hr[0] = v0.x; hr[1] = v0.y; hr[2] = v0.z; hr[3] = v0.w;
        hr[4] = v1.x; hr[5] = v1.y; hr[6] = v1.z; hr[7] = v1.w;
        hr[8] = v2.x; hr[9] = v2.y; hr[10] = v2.z; hr[11] = v2.w;
        hr[12] = v3.x; hr[13] = v3.y; hr[14] = v3.z; hr[15] = v3.w;
    }
#pragma unroll
    for (int j = 0; j < 16; ++j) hr[j] = hr[j] * av[j] + cv[j];
    for (int it = 0; it < K_HOPS; ++it) {
        float tmp[16];
#pragma unroll
        for (int j = 0; j < 16; ++j) {
            float a = bls[j];
#pragma unroll
            for (int k = 0; k < 16; ++k) a = fmaf(hr[k], wl[k * 16 + j], a);
            tmp[j] = fmaxf(a, 0.0f);
        }
#pragma unroll
        for (int j = 0; j < 16; ++j) hr[j] = ALPHA * tmp[j] + (1.0f - ALPHA) * hr[j];
    }
    {
        float4* hp = reinterpret_cast<float4*>(h + (size_t)node * H);
        hp[0] = make_float4(hr[0], hr[1], hr[2], hr[3]);
        hp[1] = make_float4(hr[4], hr[5], hr[6], hr[7]);
        hp[2] = make_float4(hr[8], hr[9], hr[10], hr[11]);
        hp[3] = make_float4(hr[12], hr[13], hr[14], hr[15]);
        float4* zp = reinterpret_cast<float4*>(agg2 + (size_t)node * H);
        float4 z4 = make_float4(0.f, 0.f, 0.f, 0.f);
        zp[0] = z4; zp[1] = z4; zp[2] = z4; zp[3] = z4;
    }
}

// ---------------- final: (agg2 + dinv^2*h) @ W2 + b2 -> log_softmax ----------------
__global__ __launch_bounds__(256) void k_final(const float* __restrict__ agg2,
                                               const float* __restrict__ h,
                                               const float* __restrict__ dinv,
                                               const float* __restrict__ W2,
                                               const float* __restrict__ b2,
                                               float* __restrict__ out, int n) {
    __shared__ float w2s[16 * 40];
    __shared__ float b2s[40];
    __shared__ float ostage[40 * 257];   // [class][thread], pad 257 to dodge bank conflicts
    int t = threadIdx.x;
    for (int i = t; i < 640; i += 256) w2s[i] = W2[i];
    if (t < 40) b2s[t] = b2[t];
    __syncthreads();
    int node = blockIdx.x * 256 + t;
    if (node < n) {
        float g[16];
        float di = dinv[node];
        float di2 = di * di;
        const float4* ap = reinterpret_cast<const float4*>(agg2 + (size_t)node * H);
        const float4* hp = reinterpret_cast<const float4*>(h + (size_t)node * H);
#pragma unroll
        for (int r = 0; r < 4; ++r) {
            float4 a = ap[r], b = hp[r];
            g[r * 4 + 0] = a.x + di2 * b.x;
            g[r * 4 + 1] = a.y + di2 * b.y;
            g[r * 4 + 2] = a.z + di2 * b.z;
            g[r * 4 + 3] = a.w + di2 * b.w;
        }
        float z[40];
#pragma unroll
        for (int j = 0; j < 40; ++j) {
            float a = b2s[j];
#pragma unroll
            for (int k = 0; k < 16; ++k) a = fmaf(g[k], w2s[k * 40 + j], a);
            z[j] = a;
        }
        float m = z[0];
#pragma unroll
        for (int j = 1; j < 40; ++j) m = fmaxf(m, z[j]);
        float s = 0.0f;
#pragma unroll
        for (int j = 0; j < 40; ++j) s += expf(z[j] - m);
        float lse = m + logf(s);
#pragma unroll
        for (int j = 0; j < 40; ++j) ostage[j * 257 + t] = z[j] - lse;
    }
    __syncthreads();
    int nodes = n - blockIdx.x * 256;
    if (nodes > 256) nodes = 256;
    int total = nodes * 40;
    size_t base = (size_t)blockIdx.x * 256 * 40;
    for (int i = t; i < total; i += 256) {
        int nl = i / 40;
        int j = i - nl * 40;
        out[base + i] = ostage[j * 257 + nl];
    }
}

extern "C" void kernel_launch(void* const* d_in, const int* in_sizes, int n_in,
                              void* d_out, int out_size, void* d_ws, size_t ws_size,
                              hipStream_t stream) {
    const float* x     = (const float*)d_in[0];
    const int*   src   = (const int*)d_in[1];
    const int*   dst   = (const int*)d_in[2];
    const float* W1    = (const float*)d_in[3];
    const float* b1    = (const float*)d_in[4];
    const float* gamma = (const float*)d_in[5];
    const float* beta  = (const float*)d_in[6];
    const float* Wl    = (const float*)d_in[7];
    const float* bl    = (const float*)d_in[8];
    const float* W2    = (const float*)d_in[9];
    const float* b2    = (const float*)d_in[10];
    float* out = (float*)d_out;

    int n = in_sizes[0] / F_IN;   // 100000
    int e = in_sizes[1];          // 3200000

    float* ws    = (float*)d_ws;
    float* deg   = ws;                 // n floats (becomes dinv)
    float* bufA  = deg + n;            // n*16 (h1, then agg2)
    float* bufB  = bufA + (size_t)n * H; // n*16 (agg1, then h)
    float* stats = bufB + (size_t)n * H; // 32

    k_init<<<2048, 256, 0, stream>>>(deg, bufB, stats, n);
    k_deg<<<(e + 255) / 256, 256, 0, stream>>>(dst, deg, e);
    k_dinv<<<(n + 255) / 256, 256, 0, stream>>>(deg, n);
    k_mm1<<<(n + 15) / 16, 256, 0, stream>>>(x, W1, bufA, n);
    k_agg<<<(int)(((long long)e * 16 + 255) / 256), 256, 0, stream>>>(src, dst, deg, bufA, bufB, e);
    k_post1<<<(n * 16 + 255) / 256, 256, 0, stream>>>(bufB, bufA, deg, b1, bufB, stats, n);
    k_bncoef<<<1, 16, 0, stream>>>(stats, gamma, beta, (float)n);
    k_hops<<<(n + 255) / 256, 256, 0, stream>>>(bufB, bufA, stats, Wl, bl, n);
    k_agg<<<(int)(((long long)e * 16 + 255) / 256), 256, 0, stream>>>(src, dst, deg, bufB, bufA, e);
    k_final<<<(n + 255) / 256, 256, 0, stream>>>(bufA, bufB, deg, W2, b2, out, n);
}

// Round 2
// 634.539 us; speedup vs baseline: 1.1773x; 1.1773x over previous
//
#include <hip/hip_runtime.h>
#include <math.h>

#define F_IN 128
#define H 16
#define C 40
#define K_HOPS 10
#define ALPHA 0.1f
#define BN_EPS 1e-5f

// ---------------- zero: cnt[n]=0, stats[32]=0 ----------------
__global__ void k_zero(int* __restrict__ cnt, float* __restrict__ stats, int n) {
    int stride = gridDim.x * blockDim.x;
    for (int i = blockIdx.x * blockDim.x + threadIdx.x; i < n; i += stride) {
        cnt[i] = 0;
        if (i < 32) stats[i] = 0.0f;
    }
}

// ---------------- degree histogram (int) ----------------
__global__ void k_deg(const int* __restrict__ dst, int* __restrict__ cnt, int e) {
    int i = blockIdx.x * blockDim.x + threadIdx.x;
    if (i < e) atomicAdd(&cnt[dst[i]], 1);
}

// ---------------- scan step 1: per-block exclusive scan + block totals ----------------
__global__ __launch_bounds__(256) void k_scan1(const int* __restrict__ cnt,
                                               int* __restrict__ offsets,
                                               int* __restrict__ partials, int n) {
    __shared__ int sd[256];
    int t = threadIdx.x;
    int i = blockIdx.x * 256 + t;
    int v = (i < n) ? cnt[i] : 0;
    sd[t] = v;
    __syncthreads();
    for (int off = 1; off < 256; off <<= 1) {
        int tmp = (t >= off) ? sd[t - off] : 0;
        __syncthreads();
        sd[t] += tmp;
        __syncthreads();
    }
    if (i < n) offsets[i] = sd[t] - v;           // exclusive
    if (t == 255) partials[blockIdx.x] = sd[255];
}

// ---------------- scan step 2: exclusive scan of block totals (single block) ----------------
__global__ __launch_bounds__(512) void k_scan2(int* __restrict__ partials, int nb) {
    __shared__ int sd[512];
    int t = threadIdx.x;
    int v = (t < nb) ? partials[t] : 0;
    sd[t] = v;
    __syncthreads();
    for (int off = 1; off < 512; off <<= 1) {
        int tmp = (t >= off) ? sd[t - off] : 0;
        __syncthreads();
        sd[t] += tmp;
        __syncthreads();
    }
    if (t < nb) partials[t] = sd[t] - v;         // exclusive
}

// ---------------- scan step 3: add block offset, init cursor, compute dinv ----------------
__global__ __launch_bounds__(256) void k_scan3(const int* __restrict__ cnt,
                                               int* __restrict__ offsets,
                                               int* __restrict__ cursor,
                                               const int* __restrict__ partials,
                                               float* __restrict__ dinv, int n) {
    int i = blockIdx.x * 256 + threadIdx.x;
    if (i >= n) return;
    int o = offsets[i] + partials[blockIdx.x];
    offsets[i] = o;
    cursor[i] = o;
    dinv[i] = rsqrtf((float)(cnt[i] + 1));       // +1 self-loop
}

// ---------------- scatter edges into CSR buckets: entries[pos] = {src, norm} ----------------
__global__ void k_scatter(const int* __restrict__ src, const int* __restrict__ dst,
                          const float* __restrict__ dinv, int* __restrict__ cursor,
                          int2* __restrict__ entries, int e) {
    int i = blockIdx.x * blockDim.x + threadIdx.x;
    if (i >= e) return;
    int s = src[i], d = dst[i];
    float nrm = dinv[s] * dinv[d];
    int pos = atomicAdd(&cursor[d], 1);
    entries[pos] = make_int2(s, __float_as_int(nrm));
}

// ---------------- h1 = x @ W1   [N,128] x [128,16] ----------------
__global__ __launch_bounds__(256) void k_mm1(const float* __restrict__ x,
                                             const float* __restrict__ W1,
                                             float* __restrict__ h1, int n) {
    __shared__ float xs[16 * 132];   // 16 nodes x 128, padded stride 132
    __shared__ float ws[128 * 16];
    int t = threadIdx.x;
    int node0 = blockIdx.x * 16;
#pragma unroll
    for (int r = 0; r < 8; ++r) {
        int idx = t + r * 256;
        int nl = idx >> 7, k = idx & 127;
        int nn = node0 + nl; if (nn >= n) nn = n - 1;
        xs[nl * 132 + k] = x[(size_t)nn * F_IN + k];
        ws[idx] = W1[idx];
    }
    __syncthreads();
    int nl = t >> 4, j = t & 15;
    float acc = 0.0f;
#pragma unroll 8
    for (int k = 0; k < 128; ++k)
        acc = fmaf(xs[nl * 132 + k], ws[k * 16 + j], acc);
    int node = node0 + nl;
    if (node < n) h1[(size_t)node * H + j] = acc;
}

// ---------------- gather conv1: agg + self + bias + ReLU + BN stats ----------------
__global__ __launch_bounds__(256) void k_gather1(const int* __restrict__ offsets,
                                                 const int* __restrict__ ends,
                                                 const int2* __restrict__ entries,
                                                 const float* __restrict__ h1,
                                                 const float* __restrict__ dinv,
                                                 const float* __restrict__ b1,
                                                 float* __restrict__ hout,
                                                 float* __restrict__ stats, int n) {
    __shared__ float sv[256], sq[256];
    int t = threadIdx.x;
    int idx = blockIdx.x * 256 + t;
    int node = idx >> 4, j = idx & 15;
    float v = 0.0f;
    if (node < n) {
        int k = offsets[node], end = ends[node];
        float acc = 0.0f;
        for (; k + 1 < end; k += 2) {
            int2 e0 = entries[k], e1 = entries[k + 1];
            float a0 = h1[(size_t)e0.x * H + j];
            float a1 = h1[(size_t)e1.x * H + j];
            acc = fmaf(a0, __int_as_float(e0.y), acc);
            acc = fmaf(a1, __int_as_float(e1.y), acc);
        }
        if (k < end) {
            int2 e0 = entries[k];
            acc = fmaf(h1[(size_t)e0.x * H + j], __int_as_float(e0.y), acc);
        }
        float di = dinv[node];
        v = acc + di * di * h1[(size_t)node * H + j] + b1[j];
        v = fmaxf(v, 0.0f);
        hout[idx] = v;
    }
    sv[t] = v; sq[t] = v * v;
    __syncthreads();
    if (t < 16) {
        float s0 = 0.0f, s1 = 0.0f;
#pragma unroll
        for (int r = 0; r < 16; ++r) { s0 += sv[r * 16 + t]; s1 += sq[r * 16 + t]; }
        atomicAdd(&stats[t], s0);
        atomicAdd(&stats[16 + t], s1);
    }
}

// ---------------- BN coefficients ----------------
__global__ void k_bncoef(float* __restrict__ stats, const float* __restrict__ gamma,
                         const float* __restrict__ beta, float nf) {
    int j = threadIdx.x;
    if (j < 16) {
        float mean = stats[j] / nf;
        float var = stats[16 + j] / nf - mean * mean;
        float a = gamma[j] * rsqrtf(var + BN_EPS);
        float c = beta[j] - mean * a;
        stats[j] = a;
        stats[16 + j] = c;
    }
}

// ---------------- BN apply + K_HOPS residual blocks ----------------
__global__ __launch_bounds__(256) void k_hops(float* __restrict__ h,
                                              const float* __restrict__ stats,
                                              const float* __restrict__ Wl,
                                              const float* __restrict__ bl, int n) {
    __shared__ float wl[256], bls[16], av[16], cv[16];
    int t = threadIdx.x;
    wl[t] = Wl[t];
    if (t < 16) { bls[t] = bl[t]; av[t] = stats[t]; cv[t] = stats[16 + t]; }
    __syncthreads();
    int node = blockIdx.x * 256 + t;
    if (node >= n) return;
    float hr[16];
    {
        const float4* hp = reinterpret_cast<const float4*>(h + (size_t)node * H);
        float4 v0 = hp[0], v1 = hp[1], v2 = hp[2], v3 = hp[3];
        hr[0] = v0.x; hr[1] = v0.y; hr[2] = v0.z; hr[3] = v0.w;
        hr[4] = v1.x; hr[5] = v1.y; hr[6] = v1.z; hr[7] = v1.w;
        hr[8] = v2.x; hr[9] = v2.y; hr[10] = v2.z; hr[11] = v2.w;
        hr[12] = v3.x; hr[13] = v3.y; hr[14] = v3.z; hr[15] = v3.w;
    }
#pragma unroll
    for (int j = 0; j < 16; ++j) hr[j] = hr[j] * av[j] + cv[j];
    for (int it = 0; it < K_HOPS; ++it) {
        float tmp[16];
#pragma unroll
        for (int j = 0; j < 16; ++j) {
            float a = bls[j];
#pragma unroll
            for (int k = 0; k < 16; ++k) a = fmaf(hr[k], wl[k * 16 + j], a);
            tmp[j] = fmaxf(a, 0.0f);
        }
#pragma unroll
        for (int j = 0; j < 16; ++j) hr[j] = ALPHA * tmp[j] + (1.0f - ALPHA) * hr[j];
    }
    {
        float4* hp = reinterpret_cast<float4*>(h + (size_t)node * H);
        hp[0] = make_float4(hr[0], hr[1], hr[2], hr[3]);
        hp[1] = make_float4(hr[4], hr[5], hr[6], hr[7]);
        hp[2] = make_float4(hr[8], hr[9], hr[10], hr[11]);
        hp[3] = make_float4(hr[12], hr[13], hr[14], hr[15]);
    }
}

// ---------------- gather conv2: agg + self-loop (no bias here; W2/b2 in k_final) ----------------
__global__ __launch_bounds__(256) void k_gather2(const int* __restrict__ offsets,
                                                 const int* __restrict__ ends,
                                                 const int2* __restrict__ entries,
                                                 const float* __restrict__ h,
                                                 const float* __restrict__ dinv,
                                                 float* __restrict__ agg, int n) {
    int idx = blockIdx.x * 256 + threadIdx.x;
    int node = idx >> 4, j = idx & 15;
    if (node >= n) return;
    int k = offsets[node], end = ends[node];
    float acc = 0.0f;
    for (; k + 1 < end; k += 2) {
        int2 e0 = entries[k], e1 = entries[k + 1];
        float a0 = h[(size_t)e0.x * H + j];
        float a1 = h[(size_t)e1.x * H + j];
        acc = fmaf(a0, __int_as_float(e0.y), acc);
        acc = fmaf(a1, __int_as_float(e1.y), acc);
    }
    if (k < end) {
        int2 e0 = entries[k];
        acc = fmaf(h[(size_t)e0.x * H + j], __int_as_float(e0.y), acc);
    }
    float di = dinv[node];
    agg[idx] = acc + di * di * h[(size_t)node * H + j];
}

// ---------------- final: agg2 @ W2 + b2 -> log_softmax ----------------
__global__ __launch_bounds__(256) void k_final(const float* __restrict__ agg2,
                                               const float* __restrict__ W2,
                                               const float* __restrict__ b2,
                                               float* __restrict__ out, int n) {
    __shared__ float w2s[16 * 40];
    __shared__ float b2s[40];
    __shared__ float ostage[40 * 257];
    int t = threadIdx.x;
    for (int i = t; i < 640; i += 256) w2s[i] = W2[i];
    if (t < 40) b2s[t] = b2[t];
    __syncthreads();
    int node = blockIdx.x * 256 + t;
    if (node < n) {
        float g[16];
        const float4* ap = reinterpret_cast<const float4*>(agg2 + (size_t)node * H);
#pragma unroll
        for (int r = 0; r < 4; ++r) {
            float4 a = ap[r];
            g[r * 4 + 0] = a.x; g[r * 4 + 1] = a.y; g[r * 4 + 2] = a.z; g[r * 4 + 3] = a.w;
        }
        float z[40];
#pragma unroll
        for (int j = 0; j < 40; ++j) {
            float a = b2s[j];
#pragma unroll
            for (int k = 0; k < 16; ++k) a = fmaf(g[k], w2s[k * 40 + j], a);
            z[j] = a;
        }
        float m = z[0];
#pragma unroll
        for (int j = 1; j < 40; ++j) m = fmaxf(m, z[j]);
        float s = 0.0f;
#pragma unroll
        for (int j = 0; j < 40; ++j) s += expf(z[j] - m);
        float lse = m + logf(s);
#pragma unroll
        for (int j = 0; j < 40; ++j) ostage[j * 257 + t] = z[j] - lse;
    }
    __syncthreads();
    int nodes = n - blockIdx.x * 256;
    if (nodes > 256) nodes = 256;
    int total = nodes * 40;
    size_t base = (size_t)blockIdx.x * 256 * 40;
    for (int i = t; i < total; i += 256) {
        int nl = i / 40;
        int j = i - nl * 40;
        out[base + i] = ostage[j * 257 + nl];
    }
}

extern "C" void kernel_launch(void* const* d_in, const int* in_sizes, int n_in,
                              void* d_out, int out_size, void* d_ws, size_t ws_size,
                              hipStream_t stream) {
    const float* x     = (const float*)d_in[0];
    const int*   src   = (const int*)d_in[1];
    const int*   dst   = (const int*)d_in[2];
    const float* W1    = (const float*)d_in[3];
    const float* b1    = (const float*)d_in[4];
    const float* gamma = (const float*)d_in[5];
    const float* beta  = (const float*)d_in[6];
    const float* Wl    = (const float*)d_in[7];
    const float* bl    = (const float*)d_in[8];
    const float* W2    = (const float*)d_in[9];
    const float* b2    = (const float*)d_in[10];
    float* out = (float*)d_out;

    int n = in_sizes[0] / F_IN;   // 100000
    int e = in_sizes[1];          // 3200000

    int nAlign = (n + 7) & ~7;    // keep 8B alignment of segments

    char* wsb = (char*)d_ws;
    int*   cnt      = (int*)wsb;                       wsb += (size_t)nAlign * 4;
    int*   offsets  = (int*)wsb;                       wsb += (size_t)nAlign * 4;
    int*   cursor   = (int*)wsb;                       wsb += (size_t)nAlign * 4;
    float* dinv     = (float*)wsb;                     wsb += (size_t)nAlign * 4;
    int*   partials = (int*)wsb;                       wsb += 1024 * 4;
    float* stats    = (float*)wsb;                     wsb += 64 * 4;
    int2*  entries  = (int2*)wsb;                      wsb += (size_t)e * 8;
    float* h1       = (float*)wsb;                     wsb += (size_t)nAlign * H * 4;
    float* hbuf     = (float*)wsb;                     wsb += (size_t)nAlign * H * 4;
    float* agg2     = (float*)wsb;                     wsb += (size_t)nAlign * H * 4;

    int nb = (n + 255) / 256;     // 391 scan blocks (must be <= 512)

    k_zero<<<256, 256, 0, stream>>>(cnt, stats, n);
    k_deg<<<(e + 255) / 256, 256, 0, stream>>>(dst, cnt, e);
    k_scan1<<<nb, 256, 0, stream>>>(cnt, offsets, partials, n);
    k_scan2<<<1, 512, 0, stream>>>(partials, nb);
    k_scan3<<<nb, 256, 0, stream>>>(cnt, offsets, cursor, partials, dinv, n);
    k_scatter<<<(e + 255) / 256, 256, 0, stream>>>(src, dst, dinv, cursor, entries, e);
    k_mm1<<<(n + 15) / 16, 256, 0, stream>>>(x, W1, h1, n);
    k_gather1<<<(n * 16 + 255) / 256, 256, 0, stream>>>(offsets, cursor, entries, h1, dinv, b1, hbuf, stats, n);
    k_bncoef<<<1, 16, 0, stream>>>(stats, gamma, beta, (float)n);
    k_hops<<<(n + 255) / 256, 256, 0, stream>>>(hbuf, stats, Wl, bl, n);
    k_gather2<<<(n * 16 + 255) / 256, 256, 0, stream>>>(offsets, cursor, entries, hbuf, dinv, agg2, n);
    k_final<<<(n + 255) / 256, 256, 0, stream>>>(agg2, W2, b2, out, n);
}